// Round 19
// baseline (248.780 us; speedup 1.0000x reference)
//
#include <hip/hip_runtime.h>
#include <math.h>

// MultiheadSelfAttention: T=4,H=32,W=32,C=1536,HD=64,NH=24,TXT=256,G=8
// tokens: 4096 visual + 256 text = 4352.  Grouped seqs: 8 x (512+256=768).
//
// Round 19 (from R18 @222.1us; prep-v2 proven neutral, kept). The one
// >=20us lever left: gemm1 phase-split schedule.
//  - gemm1 v6: 256x256 tile, BK=64, 2 buffers (128KB LDS, 1 block/CU),
//    8 waves (2Mx4N, wave=128x64, acc[8][4]). ONE vmcnt(0)+barrier per
//    K-tile (24 total; loads get a full K-tile of cover), staging of
//    K-tile t+1 issued progressively across t's 4 compute phases
//    (16 MFMA each, setprio-wrapped -> wave role diversity). Attn-proven
//    slot^(row&7) LDS swizzle (2-way banks). Grid 306 bijective XCD.
//  - everything else byte-identical to R18.

#define DEVI static __device__ __forceinline__

typedef __attribute__((ext_vector_type(8))) short short8;
typedef __attribute__((ext_vector_type(8))) unsigned short ushort8;
typedef __attribute__((ext_vector_type(4))) float f32x4;

DEVI unsigned short f2bf(float f) {
  union { float f; unsigned u; } v; v.f = f;
  unsigned r = v.u + 0x7fffu + ((v.u >> 16) & 1u);
  return (unsigned short)(r >> 16);
}
DEVI float bf2f(unsigned short h) {
  union { unsigned u; float f; } v; v.u = ((unsigned)h) << 16;
  return v.f;
}
DEVI void gl_lds16(const void* g, void* l) {
  __builtin_amdgcn_global_load_lds(
      (const __attribute__((address_space(1))) void*)g,
      (__attribute__((address_space(3))) void*)l, 16, 0, 0);
}

// ---------------- 1) prep v2: packx + transpose(Wqkv) + transpose(Wout) ----
__global__ __launch_bounds__(256) void prep_kernel(
    const float* __restrict__ vis, const float* __restrict__ txt,
    unsigned short* __restrict__ X,
    const float* __restrict__ Wqkv, unsigned short* __restrict__ WqkvT,
    const float* __restrict__ Wout, unsigned short* __restrict__ WoutT) {
  __shared__ unsigned short t[64 * 72];
  const int bid = blockIdx.x, tid = threadIdx.x;
  if (bid < 3264) {
    int i = (bid * 256 + tid) * 8;
    const int VN = 4096 * 1536;
    const float* src = (i < VN) ? (vis + i) : (txt + (i - VN));
    float4 v0 = *(const float4*)src;
    float4 v1 = *(const float4*)(src + 4);
    ushort8 o;
    o[0] = f2bf(v0.x); o[1] = f2bf(v0.y); o[2] = f2bf(v0.z); o[3] = f2bf(v0.w);
    o[4] = f2bf(v1.x); o[5] = f2bf(v1.y); o[6] = f2bf(v1.z); o[7] = f2bf(v1.w);
    *(ushort8*)&X[i] = o;
    return;
  }
  const float* in; unsigned short* out; int Cn, bx, by;
  if (bid < 4992) {
    int b = bid - 3264; bx = b % 72; by = b / 72;
    in = Wqkv; out = WqkvT; Cn = 4608;
  } else {
    int b = bid - 4992; bx = b % 24; by = b / 24;
    in = Wout; out = WoutT; Cn = 1536;
  }
  const int R = 1536;
  const int r0 = by * 64, c0 = bx * 64;
#pragma unroll
  for (int i = 0; i < 4; i++) {
    int c = i * 256 + tid;
    int r = c >> 4, ch = c & 15;
    float4 v = *(const float4*)&in[(size_t)(r0 + r) * Cn + c0 + ch * 4];
    t[r * 72 + ch * 4 + 0] = f2bf(v.x);
    t[r * 72 + ch * 4 + 1] = f2bf(v.y);
    t[r * 72 + ch * 4 + 2] = f2bf(v.z);
    t[r * 72 + ch * 4 + 3] = f2bf(v.w);
  }
  __syncthreads();
#pragma unroll
  for (int i = 0; i < 2; i++) {
    int c = i * 256 + tid;
    int cc = c >> 3, tch = c & 7;
    ushort8 o;
#pragma unroll
    for (int j = 0; j < 8; j++) o[j] = t[(tch * 8 + j) * 72 + cc];
    *(ushort8*)&out[(size_t)(c0 + cc) * R + r0 + tch * 8] = o;
  }
}

// ---------------- 3) GEMM1 v6: qkv = X @ WqkvT^T + b ----------------
// 256x256, BK=64, phase-split, progressive staging, 1 vmcnt(0)+bar per tile.
__global__ __launch_bounds__(512, 2) void gemm1_kernel(
    const unsigned short* __restrict__ A, const unsigned short* __restrict__ BT,
    const float* __restrict__ bias, unsigned short* __restrict__ C) {
  const int N = 4608, K = 1536;
  __shared__ __align__(16) unsigned short lA[2][256 * 64];
  __shared__ __align__(16) unsigned short lB[2][256 * 64];
  const int tid = threadIdx.x;
  const int wave = tid >> 6, lane = tid & 63;
  // bijective xcd swizzle: nwg=306, q=38, r=2 (R12-proven)
  const int xcd = blockIdx.x & 7, within = blockIdx.x >> 3;
  const int work = ((xcd < 2) ? xcd * 39 : 78 + (xcd - 2) * 38) + within;
  const int m0 = (work / 18) * 256, n0 = (work % 18) * 256;
  const int wm = wave >> 2, wn = wave & 3;
  const int l15 = lane & 15, h4 = lane >> 4, swz = l15 & 7;

  f32x4 acc[8][4];
#pragma unroll
  for (int m = 0; m < 8; m++)
#pragma unroll
    for (int n = 0; n < 4; n++) acc[m][n] = {0.f, 0.f, 0.f, 0.f};

  // staging: 2048 chunks/operand-tile; group g: cc = g*512 + tid;
  // row = cc>>3, LDS slot = cc&7 holds global k-chunk (slot ^ (row&7)).
  int grow[4], gsrc[4];
#pragma unroll
  for (int g = 0; g < 4; g++) {
    int cc = g * 512 + tid;
    grow[g] = cc >> 3;
    gsrc[g] = ((cc & 7) ^ ((cc >> 3) & 7)) * 8;
  }
  const int ldst = wave * 512;  // + g*4096 shorts (uniform per wave)

  auto stageg = [&](int k0, int b, int g) {
    gl_lds16(A + (size_t)(m0 + grow[g]) * K + k0 + gsrc[g],
             &lA[b][g * 4096 + ldst]);
    gl_lds16(BT + (size_t)(n0 + grow[g]) * K + k0 + gsrc[g],
             &lB[b][g * 4096 + ldst]);
  };

  // fragment reads: row*64 + ((kk*4+h4)^swz)*8   (row&7 == l15&7 == swz)
  const int arow = (wm * 128 + l15) * 64;
  const int brow = (wn * 64 + l15) * 64;
  const int ka0 = ((0 + h4) ^ swz) * 8;
  const int ka1 = ((4 + h4) ^ swz) * 8;

  stageg(0, 0, 0); stageg(0, 0, 1); stageg(0, 0, 2); stageg(0, 0, 3);
  const int nk = 24;
  for (int t = 0; t < nk; t++) {
    const int c = t & 1;
    asm volatile("s_waitcnt vmcnt(0) lgkmcnt(0)" ::: "memory");
    __builtin_amdgcn_s_barrier();
    const int kn = (t + 1) << 6;
    short8 bfr[4][2];
    if (t + 1 < nk) stageg(kn, c ^ 1, 0);
#pragma unroll
    for (int n = 0; n < 4; n++) {
      bfr[n][0] = *(const short8*)&lB[c][brow + n * 1024 + ka0];
      bfr[n][1] = *(const short8*)&lB[c][brow + n * 1024 + ka1];
    }
#pragma unroll
    for (int p = 0; p < 4; p++) {
      if (p > 0 && t + 1 < nk) stageg(kn, c ^ 1, p);
      short8 af0k0 = *(const short8*)&lA[c][arow + (2 * p + 0) * 1024 + ka0];
      short8 af0k1 = *(const short8*)&lA[c][arow + (2 * p + 0) * 1024 + ka1];
      short8 af1k0 = *(const short8*)&lA[c][arow + (2 * p + 1) * 1024 + ka0];
      short8 af1k1 = *(const short8*)&lA[c][arow + (2 * p + 1) * 1024 + ka1];
      __builtin_amdgcn_s_setprio(1);
#pragma unroll
      for (int n = 0; n < 4; n++) {
        acc[2 * p + 0][n] = __builtin_amdgcn_mfma_f32_16x16x32_bf16(
            af0k0, bfr[n][0], acc[2 * p + 0][n], 0, 0, 0);
        acc[2 * p + 0][n] = __builtin_amdgcn_mfma_f32_16x16x32_bf16(
            af0k1, bfr[n][1], acc[2 * p + 0][n], 0, 0, 0);
        acc[2 * p + 1][n] = __builtin_amdgcn_mfma_f32_16x16x32_bf16(
            af1k0, bfr[n][0], acc[2 * p + 1][n], 0, 0, 0);
        acc[2 * p + 1][n] = __builtin_amdgcn_mfma_f32_16x16x32_bf16(
            af1k1, bfr[n][1], acc[2 * p + 1][n], 0, 0, 0);
      }
      __builtin_amdgcn_s_setprio(0);
    }
  }
#pragma unroll
  for (int m = 0; m < 8; m++) {
#pragma unroll
    for (int r = 0; r < 4; r++) {
      int row = m0 + wm * 128 + m * 16 + h4 * 4 + r;
#pragma unroll
      for (int n = 0; n < 4; n++) {
        int col = n0 + wn * 64 + n * 16 + l15;
        C[(size_t)row * N + col] = f2bf(acc[m][n][r] + bias[col]);
      }
    }
  }
}

// ---------------- 7) GEMM2 fused, 128x128 (R16) ----------------
__global__ __launch_bounds__(256, 8) void gemm2_fused_kernel(
    const unsigned short* __restrict__ Og, const unsigned short* __restrict__ Ytext,
    const unsigned short* __restrict__ BT, const float* __restrict__ bias,
    float* __restrict__ C) {
  const int N = 1536, K = 1536;
  __shared__ __align__(16) unsigned short lA[2][128 * 32];
  __shared__ __align__(16) unsigned short lB[2][128 * 32];
  const int tid = threadIdx.x;
  const int wave = tid >> 6, lane = tid & 63;
  const int xcd = blockIdx.x & 7, within = blockIdx.x >> 3;
  const int work = xcd * 51 + within;          // 408 = 8*51 exact
  const int mt = work / 12;
  const int m0 = mt * 128, n0 = (work % 12) * 128;
  const int wr = wave >> 1, wc = wave & 1;
  const int l15 = lane & 15, h4 = lane >> 4;
  const bool istext = (mt >= 32);              // rows 4096..4351

  f32x4 acc[4][4];
#pragma unroll
  for (int m = 0; m < 4; m++)
#pragma unroll
    for (int n = 0; n < 4; n++) acc[m][n] = {0.f, 0.f, 0.f, 0.f};

  const int cc0 = wave * 64 + lane, cc1 = cc0 + 256;
  const int r0c = cc0 >> 2, q0c = (cc0 & 3) ^ ((r0c >> 1) & 3);
  const int r1c = cc1 >> 2, q1c = (cc1 & 3) ^ ((r1c >> 1) & 3);
  const int kq0 = q0c * 8, kq1 = q1c * 8;

  auto vbase = [&](int tok) -> size_t {
    int t = tok >> 10, hh = (tok >> 5) & 31, ww = tok & 31;
    int g = ((t >> 1) * 2 + (hh >> 4)) * 2 + (ww >> 4);
    int s = ((t & 1) * 16 + (hh & 15)) * 16 + (ww & 15);
    return (size_t)g * 1179648 + (size_t)s * 64;
  };
  size_t ab0 = 0, ab1 = 0;
  const unsigned short *at0 = nullptr, *at1 = nullptr;
  if (istext) {
    at0 = Ytext + (size_t)(m0 - 4096 + r0c) * 1536 + kq0;
    at1 = Ytext + (size_t)(m0 - 4096 + r1c) * 1536 + kq1;
  } else {
    ab0 = vbase(m0 + r0c);
    ab1 = vbase(m0 + r1c);
  }
  const unsigned short* b0 = BT + (size_t)(n0 + r0c) * K + kq0;
  const unsigned short* b1 = BT + (size_t)(n0 + r1c) * K + kq1;

  const int sw = (l15 >> 1) & 3;
  const int aoff = (wr * 64 + l15) * 32 + (h4 ^ sw) * 8;
  const int boff = (wc * 64 + l15) * 32 + (h4 ^ sw) * 8;

  auto stage = [&](int k0, int b) {
    if (istext) {
      gl_lds16(at0 + k0, &lA[b][wave * 512]);
      gl_lds16(at1 + k0, &lA[b][2048 + wave * 512]);
    } else {
      int kp0 = k0 + kq0, kp1 = k0 + kq1;
      gl_lds16(Og + ab0 + (size_t)(kp0 >> 6) * 49152 + (kp0 & 63),
               &lA[b][wave * 512]);
      gl_lds16(Og + ab1 + (size_t)(kp1 >> 6) * 49152 + (kp1 & 63),
               &lA[b][2048 + wave * 512]);
    }
    gl_lds16(b0 + k0, &lB[b][wave * 512]);
    gl_lds16(b1 + k0, &lB[b][2048 + wave * 512]);
  };

  stage(0, 0);
  const int nk = K >> 5;
  for (int t = 0; t < nk; t++) {
    const int cur = t & 1;
    __syncthreads();
    if (t + 1 < nk) stage((t + 1) << 5, cur ^ 1);
    short8 af[4], bfr[4];
#pragma unroll
    for (int m = 0; m < 4; m++) af[m] = *(const short8*)&lA[cur][aoff + m * 512];
#pragma unroll
    for (int n = 0; n < 4; n++) bfr[n] = *(const short8*)&lB[cur][boff + n * 512];
#pragma unroll
    for (int m = 0; m < 4; m++)
#pragma unroll
      for (int n = 0; n < 4; n++)
        acc[m][n] = __builtin_amdgcn_mfma_f32_16x16x32_bf16(af[m], bfr[n],
                                                            acc[m][n], 0, 0, 0);
  }
#pragma unroll
  for (int m = 0; m < 4; m++) {
#pragma unroll
    for (int r = 0; r < 4; r++) {
      int row = m0 + wr * 64 + m * 16 + h4 * 4 + r;
#pragma unroll
      for (int n = 0; n < 4; n++) {
        int col = n0 + wc * 64 + n * 16 + l15;
        C[(size_t)row * N + col] = acc[m][n][r] + bias[col];
      }
    }
  }
}

// ---------------- 4) LN + rope + scatter, vectorized ----------------
__global__ __launch_bounds__(256) void lnrope_kernel(
    const unsigned short* __restrict__ qkv, const float* __restrict__ rope,
    const float* __restrict__ qgam, const float* __restrict__ qbet,
    const float* __restrict__ kgam, const float* __restrict__ kbet,
    unsigned short* __restrict__ qg, unsigned short* __restrict__ kgo,
    unsigned short* __restrict__ vg) {
  const int wid = blockIdx.x * 4 + (threadIdx.x >> 6);
  const int lane = threadIdx.x & 63;
  const int tok = wid / 3, hg = wid - tok * 3;
  const int gl = lane & 7, hh = lane >> 3;
  const int head = hg * 8 + hh;

  const unsigned short* rowp = qkv + (size_t)tok * 4608 + head * 64 + gl * 8;
  short8 qv8 = *(const short8*)rowp;
  short8 kv8 = *(const short8*)(rowp + 1536);
  short8 vv8 = *(const short8*)(rowp + 3072);
  float q[8], k[8];
#pragma unroll
  for (int j = 0; j < 8; j++) { q[j] = bf2f(qv8[j]); k[j] = bf2f(kv8[j]); }

  float qs = 0.f, ks = 0.f;
#pragma unroll
  for (int j = 0; j < 8; j++) { qs += q[j]; ks += k[j]; }
  qs += __shfl_xor(qs, 1); qs += __shfl_xor(qs, 2); qs += __shfl_xor(qs, 4);
  ks += __shfl_xor(ks, 1); ks += __shfl_xor(ks, 2); ks += __shfl_xor(ks, 4);
  const float qmu = qs * (1.f / 64.f), kmu = ks * (1.f / 64.f);
  float qv = 0.f, kv = 0.f;
#pragma unroll
  for (int j = 0; j < 8; j++) {
    q[j] -= qmu; k[j] -= kmu;
    qv += q[j] * q[j]; kv += k[j] * k[j];
  }
  qv += __shfl_xor(qv, 1); qv += __shfl_xor(qv, 2); qv += __shfl_xor(qv, 4);
  kv += __shfl_xor(kv, 1); kv += __shfl_xor(kv, 2); kv += __shfl_xor(kv, 4);
  const float qr = rsqrtf(qv * (1.f / 64.f) + 1e-5f);
  const float kr = rsqrtf(kv * (1.f / 64.f) + 1e-5f);

  const float4* qg4 = (const float4*)(qgam + gl * 8);
  const float4* qb4 = (const float4*)(qbet + gl * 8);
  const float4* kg4 = (const float4*)(kgam + gl * 8);
  const float4* kb4 = (const float4*)(kbet + gl * 8);
  float4 qga = qg4[0], qgb = qg4[1], qba = qb4[0], qbb = qb4[1];
  float4 kga = kg4[0], kgb = kg4[1], kba = kb4[0], kbb = kb4[1];
  float qn[8], kn[8];
  const float* qgaf = &qga.x; const float* qbaf = &qba.x;
  const float* kgaf = &kga.x; const float* kbaf = &kba.x;
  const float* qgbf = &qgb.x; const float* qbbf = &qbb.x;
  const float* kgbf = &kgb.x; const float* kbbf = &kbb.x;
#pragma unroll
  for (int j = 0; j < 4; j++) {
    qn[j] = q[j] * qr * qgaf[j] + qbaf[j];
    kn[j] = k[j] * kr * kgaf[j] + kbaf[j];
    qn[4 + j] = q[4 + j] * qr * qgbf[j] + qbbf[j];
    kn[4 + j] = k[4 + j] * kr * kgbf[j] + kbbf[j];
  }

  if (tok < 4096) {
    const float4* rp = (const float4*)(rope + (size_t)tok * 128 + gl * 16);
#pragma unroll
    for (int jp = 0; jp < 4; jp++) {
      float4 R = rp[jp];
      float x0 = qn[2 * jp], x1 = qn[2 * jp + 1];
      qn[2 * jp]     = R.x * x0 + R.y * x1;
      qn[2 * jp + 1] = R.z * x0 + R.w * x1;
      x0 = kn[2 * jp]; x1 = kn[2 * jp + 1];
      kn[2 * jp]     = R.x * x0 + R.y * x1;
      kn[2 * jp + 1] = R.z * x0 + R.w * x1;
    }
  }

  ushort8 qo, ko, vo;
#pragma unroll
  for (int j = 0; j < 8; j++) {
    qo[j] = f2bf(qn[j] * 0.125f);  // fold 1/sqrt(HD)
    ko[j] = f2bf(kn[j]);
    vo[j] = (unsigned short)vv8[j];
  }

  if (tok < 4096) {
    int t = tok >> 10, hhh = (tok >> 5) & 31, ww = tok & 31;
    int g = ((t >> 1) * 2 + (hhh >> 4)) * 2 + (ww >> 4);
    int s = ((t & 1) * 16 + (hhh & 15)) * 16 + (ww & 15);
    size_t o = ((size_t)(g * 24 + head) * 768 + s) * 64 + gl * 8;
    *(ushort8*)&qg[o] = qo;
    *(ushort8*)&kgo[o] = ko;
    *(ushort8*)&vg[o] = vo;
  } else {
    int s = 512 + (tok - 4096);
#pragma unroll
    for (int g = 0; g < 8; g++) {
      size_t o = ((size_t)(g * 24 + head) * 768 + s) * 64 + gl * 8;
      *(ushort8*)&qg[o] = qo;
      *(ushort8*)&kgo[o] = ko;
      *(ushort8*)&vg[o] = vo;
    }
  }
}

// ---------------- 4b) vg[s][d] -> vgT[d][t] per (kt, gh) ----------------
__global__ __launch_bounds__(256) void transpose_v_kernel(
    const unsigned short* __restrict__ vg, unsigned short* __restrict__ vgT) {
  __shared__ unsigned short t[64][65];
  const int kt = blockIdx.x, gh = blockIdx.y, tid = threadIdx.x;
  const unsigned short* src = vg + ((size_t)gh * 768 + kt * 64) * 64;
#pragma unroll
  for (int c = tid; c < 512; c += 256) {
    int r = c >> 3, ch = c & 7;
    ushort8 v = *(const ushort8*)&src[r * 64 + ch * 8];
#pragma unroll
    for (int j = 0; j < 8; j++) t[r][ch * 8 + j] = v[j];
  }
  __syncthreads();
  unsigned short* dst = vgT + (size_t)gh * 64 * 768 + kt * 64;
#pragma unroll
  for (int c = tid; c < 512; c += 256) {
    int d = c >> 3, ch = c & 7;
    ushort8 o;
#pragma unroll
    for (int j = 0; j < 8; j++) o[j] = t[ch * 8 + j][d];
    *(ushort8*)&dst[d * 768 + ch * 8] = o;
  }
}

// ---------------- 5) flash attention, 128 q-rows/block ----------------
__global__ __launch_bounds__(256) void attn_kernel(
    const unsigned short* __restrict__ qg, const unsigned short* __restrict__ kg,
    const unsigned short* __restrict__ vgT, unsigned short* __restrict__ Og) {
  __shared__ __align__(16) unsigned short lK[2][64 * 64];
  __shared__ __align__(16) unsigned short lV[2][64 * 64];
  __shared__ __align__(16) unsigned short lP[4][32 * 72];
  const int tid = threadIdx.x, wave = tid >> 6, lane = tid & 63;
  const int bid = blockIdx.x;
  const int work = (bid & 7) * 144 + (bid >> 3);
  const int gh = work / 6, qt = work - gh * 6;
  const unsigned short* qb = qg + (size_t)gh * 768 * 64;
  const unsigned short* kb = kg + (size_t)gh * 768 * 64;
  const unsigned short* vb = vgT + (size_t)gh * 64 * 768;
  const int q0 = qt * 128 + wave * 16;

  const int l15 = lane & 15, h4 = lane >> 4, swz = lane & 7;

  short8 qf[2][2];
#pragma unroll
  for (int g = 0; g < 2; g++)
#pragma unroll
    for (int ks = 0; ks < 2; ks++)
      qf[g][ks] = *(const short8*)&qb[(q0 + g * 64 + l15) * 64 + ks * 32 + h4 * 8];

  f32x4 oacc[2][4];
#pragma unroll
  for (int g = 0; g < 2; g++)
#pragma unroll
    for (int n = 0; n < 4; n++) oacc[g][n] = {0.f, 0.f, 0.f, 0.f};
  float lr[2][4] = {{0.f, 0.f, 0.f, 0.f}, {0.f, 0.f, 0.f, 0.f}};

  const int cc0 = wave * 64 + lane;
  const int r0 = cc0 >> 3, sc0 = (cc0 & 7) ^ (r0 & 7);
  const int r1 = r0 + 32, sc1 = sc0;

  const int fb0 = l15 * 64 + ((h4 + 0) ^ swz) * 8;
  const int fb1 = l15 * 64 + ((h4 + 4) ^ swz) * 8;

  auto stage = [&](int kt, int b) {
    gl_lds16(kb + (kt * 64 + r0) * 64 + sc0 * 8, &lK[b][wave * 512]);
    gl_lds16(kb + (kt * 64 + r1) * 64 + sc1 * 8, &lK[b][(4 + wave) * 512]);
    gl_lds16(vb + r0 * 768 + kt * 64 + sc0 * 8, &lV[b][wave * 512]);
    gl_lds16(vb + r1 * 768 + kt * 64 + sc1 * 8, &lV[b][(4 + wave) * 512]);
  };

  stage(0, 0);
  unsigned short* lp = lP[wave];

  for (int kt = 0; kt < 12; kt++) {
    const int cur = kt & 1;
    __syncthreads();
    if (kt + 1 < 12) stage(kt + 1, cur ^ 1);

    f32x4 s[2][4];
#pragma unroll
    for (int g = 0; g < 2; g++)
#pragma unroll
      for (int n = 0; n < 4; n++) s[g][n] = {0.f, 0.f, 0.f, 0.f};
#pragma unroll
    for (int ks = 0; ks < 2; ks++) {
      const int fb = ks ? fb1 : fb0;
#pragma unroll
      for (int n = 0; n < 4; n++) {
        short8 kf = *(const short8*)&lK[cur][fb + n * 1024];
        s[0][n] = __builtin_amdgcn_mfma_f32_16x16x32_bf16(qf[0][ks], kf, s[0][n], 0, 0, 0);
        s[1][n] = __builtin_amdgcn_mfma_f32_16x16x32_bf16(qf[1][ks], kf, s[1][n], 0, 0, 0);
      }
    }

#pragma unroll
    for (int g = 0; g < 2; g++)
#pragma unroll
      for (int n = 0; n < 4; n++)
#pragma unroll
        for (int r = 0; r < 4; r++) {
          float e = __expf(s[g][n][r]);
          lr[g][r] += e;
          lp[(g * 16 + h4 * 4 + r) * 72 + n * 16 + l15] = f2bf(e);
        }
#pragma unroll
    for (int ks = 0; ks < 2; ks++) {
      const int fb = ks ? fb1 : fb0;
      short8 pf0 = *(const short8*)&lp[(0 + l15) * 72 + ks * 32 + h4 * 8];
      short8 pf1 = *(const short8*)&lp[(16 + l15) * 72 + ks * 32 + h4 * 8];
#pragma unroll
      for (int n = 0; n < 4; n++) {
        short8 vf = *(const short8*)&lV[cur][fb + n * 1024];
        oacc[0][n] = __builtin_amdgcn_mfma_f32_16x16x32_bf16(pf0, vf, oacc[0][n], 0, 0, 0);
        oacc[1][n] = __builtin_amdgcn_mfma_f32_16x16x32_bf16(pf1, vf, oacc[1][n], 0, 0, 0);
      }
    }
  }
#pragma unroll
  for (int g = 0; g < 2; g++)
#pragma unroll
    for (int r = 0; r < 4; r++) {
      lr[g][r] += __shfl_xor(lr[g][r], 1);
      lr[g][r] += __shfl_xor(lr[g][r], 2);
      lr[g][r] += __shfl_xor(lr[g][r], 4);
      lr[g][r] += __shfl_xor(lr[g][r], 8);
    }
#pragma unroll
  for (int g = 0; g < 2; g++)
#pragma unroll
    for (int r = 0; r < 4; r++) {
      int row = q0 + g * 64 + h4 * 4 + r;
      float inv = 1.0f / lr[g][r];
#pragma unroll
      for (int n = 0; n < 4; n++)
        Og[((size_t)gh * 768 + row) * 64 + n * 16 + l15] = f2bf(oacc[g][n][r] * inv);
    }
}

// ---------------- 6) text mean -> Ytext[256][1536] ----------------
__global__ __launch_bounds__(256) void textmean_kernel(
    const unsigned short* __restrict__ Og, unsigned short* __restrict__ Ytext) {
  const int w = blockIdx.x * 4 + (threadIdx.x >> 6);
  const int lane = threadIdx.x & 63;
  const int tt = w / 24, h = w - tt * 24;
  float acc = 0.f;
#pragma unroll
  for (int g = 0; g < 8; g++)
    acc += bf2f(Og[((size_t)(g * 24 + h) * 768 + 512 + tt) * 64 + lane]);
  Ytext[(size_t)tt * 1536 + h * 64 + lane] = f2bf(acc * 0.125f);
}

extern "C" void kernel_launch(void* const* d_in, const int* in_sizes, int n_in,
                              void* d_out, int out_size, void* d_ws, size_t ws_size,
                              hipStream_t stream) {
  const float* vis  = (const float*)d_in[0];
  const float* txt  = (const float*)d_in[1];
  const float* rope = (const float*)d_in[2];
  const float* Wqkv = (const float*)d_in[5];
  const float* bqkv = (const float*)d_in[6];
  const float* qgam = (const float*)d_in[7];
  const float* qbet = (const float*)d_in[8];
  const float* kgam = (const float*)d_in[9];
  const float* kbet = (const float*)d_in[10];
  const float* Wout = (const float*)d_in[11];
  const float* bout = (const float*)d_in[12];

  char* ws = (char*)d_ws;
  size_t off = 0;
  auto alloc = [&](size_t bytes) {
    void* p = ws + off;
    off += (bytes + 255) & ~(size_t)255;
    return p;
  };
  unsigned short* X     = (unsigned short*)alloc(4352ull * 1536 * 2);
  unsigned short* WqkvT = (unsigned short*)alloc(4608ull * 1536 * 2);
  unsigned short* WoutT = (unsigned short*)alloc(1536ull * 1536 * 2);
  unsigned short* qkv   = (unsigned short*)alloc(4352ull * 4608 * 2);
  unsigned short* qgb   = (unsigned short*)alloc(192ull * 768 * 64 * 2);
  unsigned short* kgb   = (unsigned short*)alloc(192ull * 768 * 64 * 2);
  unsigned short* vgT   = (unsigned short*)alloc(192ull * 64 * 768 * 2);
  unsigned short* vg    = X;    // overlay (X+WqkvT dead after gemm1)
  unsigned short* Ogb   = qkv;  // reuse: qkv dead after lnrope
  unsigned short* Ytext = X;    // reuse: vg dead after transpose_v

  prep_kernel<<<5568, 256, 0, stream>>>(vis, txt, X, Wqkv, WqkvT, Wout, WoutT);
  gemm1_kernel<<<dim3(306), 512, 0, stream>>>(X, WqkvT, bqkv, qkv);
  lnrope_kernel<<<3264, 256, 0, stream>>>(qkv, rope, qgam, qbet, kgam, kbet, qgb, kgb, vg);
  transpose_v_kernel<<<dim3(12, 192), 256, 0, stream>>>(vg, vgT);
  attn_kernel<<<1152, 256, 0, stream>>>(qgb, kgb, vgT, Ogb);
  textmean_kernel<<<1536, 256, 0, stream>>>(Ogb, Ytext);
  gemm2_fused_kernel<<<dim3(408), 256, 0, stream>>>(
      Ogb, Ytext, WoutT, bout, (float*)d_out);
}

// Round 20
// 221.484 us; speedup vs baseline: 1.1232x; 1.1232x over previous
//
#include <hip/hip_runtime.h>
#include <math.h>

// MultiheadSelfAttention: T=4,H=32,W=32,C=1536,HD=64,NH=24,TXT=256,G=8
// tokens: 4096 visual + 256 text = 4352.  Grouped seqs: 8 x (512+256=768).
//
// Round 20 FINAL (R19's 256^2/BK=64 phase-split regressed gemm1 94->119us:
// third confirmation that <=1 block/CU loses ~25% on this problem no
// matter the intra-block schedule). Revert to R18 (best, 222.1us):
//  prep v2 + gemm1 v4 (256x128, 2-phase, slot-XOR swizzle, 2D XCD regions)
//  + lnrope vectorized + transpose_v + attn (128 q-rows, fixed-max softmax,
//  chunk-XOR staging, XCD-grouped) + textmean + gemm2_fused 128^2 (gather
//  ungroup/Ytext via per-lane gl_lds sources).

#define DEVI static __device__ __forceinline__

typedef __attribute__((ext_vector_type(8))) short short8;
typedef __attribute__((ext_vector_type(8))) unsigned short ushort8;
typedef __attribute__((ext_vector_type(4))) float f32x4;

DEVI unsigned short f2bf(float f) {
  union { float f; unsigned u; } v; v.f = f;
  unsigned r = v.u + 0x7fffu + ((v.u >> 16) & 1u);
  return (unsigned short)(r >> 16);
}
DEVI float bf2f(unsigned short h) {
  union { unsigned u; float f; } v; v.u = ((unsigned)h) << 16;
  return v.f;
}
DEVI void gl_lds16(const void* g, void* l) {
  __builtin_amdgcn_global_load_lds(
      (const __attribute__((address_space(1))) void*)g,
      (__attribute__((address_space(3))) void*)l, 16, 0, 0);
}

// ---------------- 1) prep v2: packx + transpose(Wqkv) + transpose(Wout) ----
// blocks [0,3264): packx(x8); [3264,4992): Wqkv^T 64x64; [4992,5568): Wout^T.
__global__ __launch_bounds__(256) void prep_kernel(
    const float* __restrict__ vis, const float* __restrict__ txt,
    unsigned short* __restrict__ X,
    const float* __restrict__ Wqkv, unsigned short* __restrict__ WqkvT,
    const float* __restrict__ Wout, unsigned short* __restrict__ WoutT) {
  __shared__ unsigned short t[64 * 72];
  const int bid = blockIdx.x, tid = threadIdx.x;
  if (bid < 3264) {
    int i = (bid * 256 + tid) * 8;
    const int VN = 4096 * 1536;
    const float* src = (i < VN) ? (vis + i) : (txt + (i - VN));
    float4 v0 = *(const float4*)src;
    float4 v1 = *(const float4*)(src + 4);
    ushort8 o;
    o[0] = f2bf(v0.x); o[1] = f2bf(v0.y); o[2] = f2bf(v0.z); o[3] = f2bf(v0.w);
    o[4] = f2bf(v1.x); o[5] = f2bf(v1.y); o[6] = f2bf(v1.z); o[7] = f2bf(v1.w);
    *(ushort8*)&X[i] = o;
    return;
  }
  const float* in; unsigned short* out; int Cn, bx, by;
  if (bid < 4992) {
    int b = bid - 3264; bx = b % 72; by = b / 72;
    in = Wqkv; out = WqkvT; Cn = 4608;
  } else {
    int b = bid - 4992; bx = b % 24; by = b / 24;
    in = Wout; out = WoutT; Cn = 1536;
  }
  const int R = 1536;
  const int r0 = by * 64, c0 = bx * 64;
#pragma unroll
  for (int i = 0; i < 4; i++) {
    int c = i * 256 + tid;
    int r = c >> 4, ch = c & 15;
    float4 v = *(const float4*)&in[(size_t)(r0 + r) * Cn + c0 + ch * 4];
    t[r * 72 + ch * 4 + 0] = f2bf(v.x);
    t[r * 72 + ch * 4 + 1] = f2bf(v.y);
    t[r * 72 + ch * 4 + 2] = f2bf(v.z);
    t[r * 72 + ch * 4 + 3] = f2bf(v.w);
  }
  __syncthreads();
#pragma unroll
  for (int i = 0; i < 2; i++) {
    int c = i * 256 + tid;
    int cc = c >> 3, tch = c & 7;
    ushort8 o;
#pragma unroll
    for (int j = 0; j < 8; j++) o[j] = t[(tch * 8 + j) * 72 + cc];
    *(ushort8*)&out[(size_t)(c0 + cc) * R + r0 + tch * 8] = o;
  }
}

// ---------------- 3) GEMM v4: C = A @ BT^T + bias ----------------
// 256x128 tile, BK=32, 2-deep LDS dbuf (48KB), 512 thr = 8 waves (4M x 2N).
template <typename OutT, int RM, int RN>
__global__ __launch_bounds__(512, 4) void gemm_bf16_kernel(
    const unsigned short* __restrict__ A, const unsigned short* __restrict__ BT,
    const float* __restrict__ bias, OutT* __restrict__ C,
    int M, int N, int K) {
  __shared__ __align__(16) unsigned short lA[2][256 * 32];
  __shared__ __align__(16) unsigned short lB[2][128 * 32];
  const int tid = threadIdx.x;
  const int wave = tid >> 6, lane = tid & 63;
  const int x = blockIdx.x & 7, seq = blockIdx.x >> 3;
  const int mt = (x >> 2) * RM + seq / RN;
  if (mt * 256 >= M) return;               // dead pad block (uniform exit)
  const int m0 = mt * 256;
  const int n0 = ((x & 3) * RN + seq % RN) * 128;
  const int wr = wave >> 1, wc = wave & 1;
  const int l15 = lane & 15, h4 = lane >> 4;

  f32x4 acc[4][4];
#pragma unroll
  for (int m = 0; m < 4; m++)
#pragma unroll
    for (int n = 0; n < 4; n++) acc[m][n] = {0.f, 0.f, 0.f, 0.f};

  const int ccA0 = tid, ccA1 = tid + 512, ccB = tid;
  const int ra0 = ccA0 >> 2, qa0 = (ccA0 & 3) ^ ((ra0 >> 1) & 3);
  const int ra1 = ccA1 >> 2, qa1 = (ccA1 & 3) ^ ((ra1 >> 1) & 3);
  const int rb  = ccB >> 2,  qb  = (ccB & 3) ^ ((rb >> 1) & 3);
  const unsigned short* a0 = A + (size_t)(m0 + ra0) * K + qa0 * 8;
  const unsigned short* a1 = A + (size_t)(m0 + ra1) * K + qa1 * 8;
  const unsigned short* b0 = BT + (size_t)(n0 + rb) * K + qb * 8;

  const int sw = (l15 >> 1) & 3;
  const int aoff = (wr * 64 + l15) * 32 + (h4 ^ sw) * 8;
  const int boff = (wc * 64 + l15) * 32 + (h4 ^ sw) * 8;

  auto stage = [&](int k0, int b) {
    gl_lds16(a0 + k0, &lA[b][wave * 512]);
    gl_lds16(a1 + k0, &lA[b][(8 + wave) * 512]);
    gl_lds16(b0 + k0, &lB[b][wave * 512]);
  };

  stage(0, 0);
  const int nk = K >> 5;
  for (int t = 0; t < nk; t++) {
    const int cur = t & 1;
    __syncthreads();
    if (t + 1 < nk) stage((t + 1) << 5, cur ^ 1);
    short8 af[4], bfr[4];
#pragma unroll
    for (int m = 0; m < 4; m++) af[m] = *(const short8*)&lA[cur][aoff + m * 512];
#pragma unroll
    for (int n = 0; n < 4; n++) bfr[n] = *(const short8*)&lB[cur][boff + n * 512];
#pragma unroll
    for (int m = 0; m < 4; m++)
#pragma unroll
      for (int n = 0; n < 4; n++)
        acc[m][n] = __builtin_amdgcn_mfma_f32_16x16x32_bf16(af[m], bfr[n],
                                                            acc[m][n], 0, 0, 0);
  }
#pragma unroll
  for (int m = 0; m < 4; m++) {
#pragma unroll
    for (int r = 0; r < 4; r++) {
      int row = m0 + wr * 64 + m * 16 + h4 * 4 + r;
#pragma unroll
      for (int n = 0; n < 4; n++) {
        int col = n0 + wc * 64 + n * 16 + l15;
        float val = acc[m][n][r] + bias[col];
        if constexpr (sizeof(OutT) == 4) C[(size_t)row * N + col] = val;
        else                             C[(size_t)row * N + col] = f2bf(val);
      }
    }
  }
}

// ---------------- 7) GEMM2 fused, 128x128: ungroup(Og)@WoutT^T+b ----------
// 4 waves (2x2), 256 thr, BK=32, 2-deep dbuf (32KB). Grid 408 = 8x51 exact.
__global__ __launch_bounds__(256, 8) void gemm2_fused_kernel(
    const unsigned short* __restrict__ Og, const unsigned short* __restrict__ Ytext,
    const unsigned short* __restrict__ BT, const float* __restrict__ bias,
    float* __restrict__ C) {
  const int N = 1536, K = 1536;
  __shared__ __align__(16) unsigned short lA[2][128 * 32];
  __shared__ __align__(16) unsigned short lB[2][128 * 32];
  const int tid = threadIdx.x;
  const int wave = tid >> 6, lane = tid & 63;
  const int xcd = blockIdx.x & 7, within = blockIdx.x >> 3;
  const int work = xcd * 51 + within;          // 408 = 8*51 exact
  const int mt = work / 12;
  const int m0 = mt * 128, n0 = (work % 12) * 128;
  const int wr = wave >> 1, wc = wave & 1;
  const int l15 = lane & 15, h4 = lane >> 4;
  const bool istext = (mt >= 32);              // rows 4096..4351

  f32x4 acc[4][4];
#pragma unroll
  for (int m = 0; m < 4; m++)
#pragma unroll
    for (int n = 0; n < 4; n++) acc[m][n] = {0.f, 0.f, 0.f, 0.f};

  const int cc0 = wave * 64 + lane, cc1 = cc0 + 256;
  const int r0c = cc0 >> 2, q0c = (cc0 & 3) ^ ((r0c >> 1) & 3);
  const int r1c = cc1 >> 2, q1c = (cc1 & 3) ^ ((r1c >> 1) & 3);
  const int kq0 = q0c * 8, kq1 = q1c * 8;

  auto vbase = [&](int tok) -> size_t {
    int t = tok >> 10, hh = (tok >> 5) & 31, ww = tok & 31;
    int g = ((t >> 1) * 2 + (hh >> 4)) * 2 + (ww >> 4);
    int s = ((t & 1) * 16 + (hh & 15)) * 16 + (ww & 15);
    return (size_t)g * 1179648 + (size_t)s * 64;
  };
  size_t ab0 = 0, ab1 = 0;
  const unsigned short *at0 = nullptr, *at1 = nullptr;
  if (istext) {
    at0 = Ytext + (size_t)(m0 - 4096 + r0c) * 1536 + kq0;
    at1 = Ytext + (size_t)(m0 - 4096 + r1c) * 1536 + kq1;
  } else {
    ab0 = vbase(m0 + r0c);
    ab1 = vbase(m0 + r1c);
  }
  const unsigned short* b0 = BT + (size_t)(n0 + r0c) * K + kq0;
  const unsigned short* b1 = BT + (size_t)(n0 + r1c) * K + kq1;

  const int sw = (l15 >> 1) & 3;
  const int aoff = (wr * 64 + l15) * 32 + (h4 ^ sw) * 8;
  const int boff = (wc * 64 + l15) * 32 + (h4 ^ sw) * 8;

  auto stage = [&](int k0, int b) {
    if (istext) {
      gl_lds16(at0 + k0, &lA[b][wave * 512]);
      gl_lds16(at1 + k0, &lA[b][2048 + wave * 512]);
    } else {
      int kp0 = k0 + kq0, kp1 = k0 + kq1;
      gl_lds16(Og + ab0 + (size_t)(kp0 >> 6) * 49152 + (kp0 & 63),
               &lA[b][wave * 512]);
      gl_lds16(Og + ab1 + (size_t)(kp1 >> 6) * 49152 + (kp1 & 63),
               &lA[b][2048 + wave * 512]);
    }
    gl_lds16(b0 + k0, &lB[b][wave * 512]);
    gl_lds16(b1 + k0, &lB[b][2048 + wave * 512]);
  };

  stage(0, 0);
  const int nk = K >> 5;
  for (int t = 0; t < nk; t++) {
    const int cur = t & 1;
    __syncthreads();
    if (t + 1 < nk) stage((t + 1) << 5, cur ^ 1);
    short8 af[4], bfr[4];
#pragma unroll
    for (int m = 0; m < 4; m++) af[m] = *(const short8*)&lA[cur][aoff + m * 512];
#pragma unroll
    for (int n = 0; n < 4; n++) bfr[n] = *(const short8*)&lB[cur][boff + n * 512];
#pragma unroll
    for (int m = 0; m < 4; m++)
#pragma unroll
      for (int n = 0; n < 4; n++)
        acc[m][n] = __builtin_amdgcn_mfma_f32_16x16x32_bf16(af[m], bfr[n],
                                                            acc[m][n], 0, 0, 0);
  }
#pragma unroll
  for (int m = 0; m < 4; m++) {
#pragma unroll
    for (int r = 0; r < 4; r++) {
      int row = m0 + wr * 64 + m * 16 + h4 * 4 + r;
#pragma unroll
      for (int n = 0; n < 4; n++) {
        int col = n0 + wc * 64 + n * 16 + l15;
        C[(size_t)row * N + col] = acc[m][n][r] + bias[col];
      }
    }
  }
}

// ---------------- 4) LN + rope + scatter, vectorized ----------------
__global__ __launch_bounds__(256) void lnrope_kernel(
    const unsigned short* __restrict__ qkv, const float* __restrict__ rope,
    const float* __restrict__ qgam, const float* __restrict__ qbet,
    const float* __restrict__ kgam, const float* __restrict__ kbet,
    unsigned short* __restrict__ qg, unsigned short* __restrict__ kgo,
    unsigned short* __restrict__ vg) {
  const int wid = blockIdx.x * 4 + (threadIdx.x >> 6);
  const int lane = threadIdx.x & 63;
  const int tok = wid / 3, hg = wid - tok * 3;
  const int gl = lane & 7, hh = lane >> 3;
  const int head = hg * 8 + hh;

  const unsigned short* rowp = qkv + (size_t)tok * 4608 + head * 64 + gl * 8;
  short8 qv8 = *(const short8*)rowp;
  short8 kv8 = *(const short8*)(rowp + 1536);
  short8 vv8 = *(const short8*)(rowp + 3072);
  float q[8], k[8];
#pragma unroll
  for (int j = 0; j < 8; j++) { q[j] = bf2f(qv8[j]); k[j] = bf2f(kv8[j]); }

  float qs = 0.f, ks = 0.f;
#pragma unroll
  for (int j = 0; j < 8; j++) { qs += q[j]; ks += k[j]; }
  qs += __shfl_xor(qs, 1); qs += __shfl_xor(qs, 2); qs += __shfl_xor(qs, 4);
  ks += __shfl_xor(ks, 1); ks += __shfl_xor(ks, 2); ks += __shfl_xor(ks, 4);
  const float qmu = qs * (1.f / 64.f), kmu = ks * (1.f / 64.f);
  float qv = 0.f, kv = 0.f;
#pragma unroll
  for (int j = 0; j < 8; j++) {
    q[j] -= qmu; k[j] -= kmu;
    qv += q[j] * q[j]; kv += k[j] * k[j];
  }
  qv += __shfl_xor(qv, 1); qv += __shfl_xor(qv, 2); qv += __shfl_xor(qv, 4);
  kv += __shfl_xor(kv, 1); kv += __shfl_xor(kv, 2); kv += __shfl_xor(kv, 4);
  const float qr = rsqrtf(qv * (1.f / 64.f) + 1e-5f);
  const float kr = rsqrtf(kv * (1.f / 64.f) + 1e-5f);

  const float4* qg4 = (const float4*)(qgam + gl * 8);
  const float4* qb4 = (const float4*)(qbet + gl * 8);
  const float4* kg4 = (const float4*)(kgam + gl * 8);
  const float4* kb4 = (const float4*)(kbet + gl * 8);
  float4 qga = qg4[0], qgb = qg4[1], qba = qb4[0], qbb = qb4[1];
  float4 kga = kg4[0], kgb = kg4[1], kba = kb4[0], kbb = kb4[1];
  float qn[8], kn[8];
  const float* qgaf = &qga.x; const float* qbaf = &qba.x;
  const float* kgaf = &kga.x; const float* kbaf = &kba.x;
  const float* qgbf = &qgb.x; const float* qbbf = &qbb.x;
  const float* kgbf = &kgb.x; const float* kbbf = &kbb.x;
#pragma unroll
  for (int j = 0; j < 4; j++) {
    qn[j] = q[j] * qr * qgaf[j] + qbaf[j];
    kn[j] = k[j] * kr * kgaf[j] + kbaf[j];
    qn[4 + j] = q[4 + j] * qr * qgbf[j] + qbbf[j];
    kn[4 + j] = k[4 + j] * kr * kgbf[j] + kbbf[j];
  }

  if (tok < 4096) {
    const float4* rp = (const float4*)(rope + (size_t)tok * 128 + gl * 16);
#pragma unroll
    for (int jp = 0; jp < 4; jp++) {
      float4 R = rp[jp];
      float x0 = qn[2 * jp], x1 = qn[2 * jp + 1];
      qn[2 * jp]     = R.x * x0 + R.y * x1;
      qn[2 * jp + 1] = R.z * x0 + R.w * x1;
      x0 = kn[2 * jp]; x1 = kn[2 * jp + 1];
      kn[2 * jp]     = R.x * x0 + R.y * x1;
      kn[2 * jp + 1] = R.z * x0 + R.w * x1;
    }
  }

  ushort8 qo, ko, vo;
#pragma unroll
  for (int j = 0; j < 8; j++) {
    qo[j] = f2bf(qn[j] * 0.125f);  // fold 1/sqrt(HD)
    ko[j] = f2bf(kn[j]);
    vo[j] = (unsigned short)vv8[j];
  }

  if (tok < 4096) {
    int t = tok >> 10, hhh = (tok >> 5) & 31, ww = tok & 31;
    int g = ((t >> 1) * 2 + (hhh >> 4)) * 2 + (ww >> 4);
    int s = ((t & 1) * 16 + (hhh & 15)) * 16 + (ww & 15);
    size_t o = ((size_t)(g * 24 + head) * 768 + s) * 64 + gl * 8;
    *(ushort8*)&qg[o] = qo;
    *(ushort8*)&kgo[o] = ko;
    *(ushort8*)&vg[o] = vo;
  } else {
    int s = 512 + (tok - 4096);
#pragma unroll
    for (int g = 0; g < 8; g++) {
      size_t o = ((size_t)(g * 24 + head) * 768 + s) * 64 + gl * 8;
      *(ushort8*)&qg[o] = qo;
      *(ushort8*)&kgo[o] = ko;
      *(ushort8*)&vg[o] = vo;
    }
  }
}

// ---------------- 4b) vg[s][d] -> vgT[d][t] per (kt, gh) ----------------
__global__ __launch_bounds__(256) void transpose_v_kernel(
    const unsigned short* __restrict__ vg, unsigned short* __restrict__ vgT) {
  __shared__ unsigned short t[64][65];
  const int kt = blockIdx.x, gh = blockIdx.y, tid = threadIdx.x;
  const unsigned short* src = vg + ((size_t)gh * 768 + kt * 64) * 64;
#pragma unroll
  for (int c = tid; c < 512; c += 256) {
    int r = c >> 3, ch = c & 7;
    ushort8 v = *(const ushort8*)&src[r * 64 + ch * 8];
#pragma unroll
    for (int j = 0; j < 8; j++) t[r][ch * 8 + j] = v[j];
  }
  __syncthreads();
  unsigned short* dst = vgT + (size_t)gh * 64 * 768 + kt * 64;
#pragma unroll
  for (int c = tid; c < 512; c += 256) {
    int d = c >> 3, ch = c & 7;
    ushort8 o;
#pragma unroll
    for (int j = 0; j < 8; j++) o[j] = t[ch * 8 + j][d];
    *(ushort8*)&dst[d * 768 + ch * 8] = o;
  }
}

// ---------------- 5) flash attention, 128 q-rows/block ----------------
__global__ __launch_bounds__(256) void attn_kernel(
    const unsigned short* __restrict__ qg, const unsigned short* __restrict__ kg,
    const unsigned short* __restrict__ vgT, unsigned short* __restrict__ Og) {
  __shared__ __align__(16) unsigned short lK[2][64 * 64];
  __shared__ __align__(16) unsigned short lV[2][64 * 64];
  __shared__ __align__(16) unsigned short lP[4][32 * 72];
  const int tid = threadIdx.x, wave = tid >> 6, lane = tid & 63;
  const int bid = blockIdx.x;
  const int work = (bid & 7) * 144 + (bid >> 3);
  const int gh = work / 6, qt = work - gh * 6;
  const unsigned short* qb = qg + (size_t)gh * 768 * 64;
  const unsigned short* kb = kg + (size_t)gh * 768 * 64;
  const unsigned short* vb = vgT + (size_t)gh * 64 * 768;
  const int q0 = qt * 128 + wave * 16;

  const int l15 = lane & 15, h4 = lane >> 4, swz = lane & 7;

  short8 qf[2][2];
#pragma unroll
  for (int g = 0; g < 2; g++)
#pragma unroll
    for (int ks = 0; ks < 2; ks++)
      qf[g][ks] = *(const short8*)&qb[(q0 + g * 64 + l15) * 64 + ks * 32 + h4 * 8];

  f32x4 oacc[2][4];
#pragma unroll
  for (int g = 0; g < 2; g++)
#pragma unroll
    for (int n = 0; n < 4; n++) oacc[g][n] = {0.f, 0.f, 0.f, 0.f};
  float lr[2][4] = {{0.f, 0.f, 0.f, 0.f}, {0.f, 0.f, 0.f, 0.f}};

  const int cc0 = wave * 64 + lane;
  const int r0 = cc0 >> 3, sc0 = (cc0 & 7) ^ (r0 & 7);
  const int r1 = r0 + 32, sc1 = sc0;

  const int fb0 = l15 * 64 + ((h4 + 0) ^ swz) * 8;
  const int fb1 = l15 * 64 + ((h4 + 4) ^ swz) * 8;

  auto stage = [&](int kt, int b) {
    gl_lds16(kb + (kt * 64 + r0) * 64 + sc0 * 8, &lK[b][wave * 512]);
    gl_lds16(kb + (kt * 64 + r1) * 64 + sc1 * 8, &lK[b][(4 + wave) * 512]);
    gl_lds16(vb + r0 * 768 + kt * 64 + sc0 * 8, &lV[b][wave * 512]);
    gl_lds16(vb + r1 * 768 + kt * 64 + sc1 * 8, &lV[b][(4 + wave) * 512]);
  };

  stage(0, 0);
  unsigned short* lp = lP[wave];

  for (int kt = 0; kt < 12; kt++) {
    const int cur = kt & 1;
    __syncthreads();
    if (kt + 1 < 12) stage(kt + 1, cur ^ 1);

    f32x4 s[2][4];
#pragma unroll
    for (int g = 0; g < 2; g++)
#pragma unroll
      for (int n = 0; n < 4; n++) s[g][n] = {0.f, 0.f, 0.f, 0.f};
#pragma unroll
    for (int ks = 0; ks < 2; ks++) {
      const int fb = ks ? fb1 : fb0;
#pragma unroll
      for (int n = 0; n < 4; n++) {
        short8 kf = *(const short8*)&lK[cur][fb + n * 1024];
        s[0][n] = __builtin_amdgcn_mfma_f32_16x16x32_bf16(qf[0][ks], kf, s[0][n], 0, 0, 0);
        s[1][n] = __builtin_amdgcn_mfma_f32_16x16x32_bf16(qf[1][ks], kf, s[1][n], 0, 0, 0);
      }
    }

#pragma unroll
    for (int g = 0; g < 2; g++)
#pragma unroll
      for (int n = 0; n < 4; n++)
#pragma unroll
        for (int r = 0; r < 4; r++) {
          float e = __expf(s[g][n][r]);
          lr[g][r] += e;
          lp[(g * 16 + h4 * 4 + r) * 72 + n * 16 + l15] = f2bf(e);
        }
#pragma unroll
    for (int ks = 0; ks < 2; ks++) {
      const int fb = ks ? fb1 : fb0;
      short8 pf0 = *(const short8*)&lp[(0 + l15) * 72 + ks * 32 + h4 * 8];
      short8 pf1 = *(const short8*)&lp[(16 + l15) * 72 + ks * 32 + h4 * 8];
#pragma unroll
      for (int n = 0; n < 4; n++) {
        short8 vf = *(const short8*)&lV[cur][fb + n * 1024];
        oacc[0][n] = __builtin_amdgcn_mfma_f32_16x16x32_bf16(pf0, vf, oacc[0][n], 0, 0, 0);
        oacc[1][n] = __builtin_amdgcn_mfma_f32_16x16x32_bf16(pf1, vf, oacc[1][n], 0, 0, 0);
      }
    }
  }
#pragma unroll
  for (int g = 0; g < 2; g++)
#pragma unroll
    for (int r = 0; r < 4; r++) {
      lr[g][r] += __shfl_xor(lr[g][r], 1);
      lr[g][r] += __shfl_xor(lr[g][r], 2);
      lr[g][r] += __shfl_xor(lr[g][r], 4);
      lr[g][r] += __shfl_xor(lr[g][r], 8);
    }
#pragma unroll
  for (int g = 0; g < 2; g++)
#pragma unroll
    for (int r = 0; r < 4; r++) {
      int row = q0 + g * 64 + h4 * 4 + r;
      float inv = 1.0f / lr[g][r];
#pragma unroll
      for (int n = 0; n < 4; n++)
        Og[((size_t)gh * 768 + row) * 64 + n * 16 + l15] = f2bf(oacc[g][n][r] * inv);
    }
}

// ---------------- 6) text mean -> Ytext[256][1536] ----------------
__global__ __launch_bounds__(256) void textmean_kernel(
    const unsigned short* __restrict__ Og, unsigned short* __restrict__ Ytext) {
  const int w = blockIdx.x * 4 + (threadIdx.x >> 6);
  const int lane = threadIdx.x & 63;
  const int tt = w / 24, h = w - tt * 24;
  float acc = 0.f;
#pragma unroll
  for (int g = 0; g < 8; g++)
    acc += bf2f(Og[((size_t)(g * 24 + h) * 768 + 512 + tt) * 64 + lane]);
  Ytext[(size_t)tt * 1536 + h * 64 + lane] = f2bf(acc * 0.125f);
}

extern "C" void kernel_launch(void* const* d_in, const int* in_sizes, int n_in,
                              void* d_out, int out_size, void* d_ws, size_t ws_size,
                              hipStream_t stream) {
  const float* vis  = (const float*)d_in[0];
  const float* txt  = (const float*)d_in[1];
  const float* rope = (const float*)d_in[2];
  const float* Wqkv = (const float*)d_in[5];
  const float* bqkv = (const float*)d_in[6];
  const float* qgam = (const float*)d_in[7];
  const float* qbet = (const float*)d_in[8];
  const float* kgam = (const float*)d_in[9];
  const float* kbet = (const float*)d_in[10];
  const float* Wout = (const float*)d_in[11];
  const float* bout = (const float*)d_in[12];

  char* ws = (char*)d_ws;
  size_t off = 0;
  auto alloc = [&](size_t bytes) {
    void* p = ws + off;
    off += (bytes + 255) & ~(size_t)255;
    return p;
  };
  unsigned short* X     = (unsigned short*)alloc(4352ull * 1536 * 2);
  unsigned short* WqkvT = (unsigned short*)alloc(4608ull * 1536 * 2);
  unsigned short* WoutT = (unsigned short*)alloc(1536ull * 1536 * 2);
  unsigned short* qkv   = (unsigned short*)alloc(4352ull * 4608 * 2);
  unsigned short* qgb   = (unsigned short*)alloc(192ull * 768 * 64 * 2);
  unsigned short* kgb   = (unsigned short*)alloc(192ull * 768 * 64 * 2);
  unsigned short* vgT   = (unsigned short*)alloc(192ull * 64 * 768 * 2);
  unsigned short* vg    = X;    // overlay (X+WqkvT dead after gemm1)
  unsigned short* Ogb   = qkv;  // reuse: qkv dead after lnrope
  unsigned short* Ytext = X;    // reuse: vg dead after transpose_v

  prep_kernel<<<5568, 256, 0, stream>>>(vis, txt, X, Wqkv, WqkvT, Wout, WoutT);
  gemm_bf16_kernel<unsigned short, 9, 9><<<dim3(648), 512, 0, stream>>>(
      X, WqkvT, bqkv, qkv, 4352, 4608, 1536);
  lnrope_kernel<<<3264, 256, 0, stream>>>(qkv, rope, qgam, qbet, kgam, kbet, qgb, kgb, vg);
  transpose_v_kernel<<<dim3(12, 192), 256, 0, stream>>>(vg, vgT);
  attn_kernel<<<1152, 256, 0, stream>>>(qgb, kgb, vgT, Ogb);
  textmean_kernel<<<1536, 256, 0, stream>>>(Ogb, Ytext);
  gemm2_fused_kernel<<<dim3(408), 256, 0, stream>>>(
      Ogb, Ytext, WoutT, bout, (float*)d_out);
}